// Round 10
// baseline (201.983 us; speedup 1.0000x reference)
//
#include <hip/hip_runtime.h>
#include <hip/hip_bf16.h>

// Shapes fixed by the problem instance.
#define BB   8
#define TT   256
#define NH   8
#define CC   16
#define HH   16
#define WW   32
#define LL   512
#define DCH  32
#define GC   8

// k_cov LDS image: 4 planes of channel-quads, entry = 8 B (4 bf16 channels).
// Plane stride 964 entries (7712 B). A-read = 2 x ds_read_b64.
#define PSC4 964   // 20 rows * 48 slots + 4 pad
// k_gate LDS image: pair-interleaved (r5 layout), stride in ushorts.
#define PSG  1736  // 864 pix + 4 pad slots  [r5-r9: 0 conflicts]

typedef __attribute__((ext_vector_type(8))) short s8b;
typedef __attribute__((ext_vector_type(4))) float f32x4;

__device__ __forceinline__ ushort f2bfu(float v) {
  __hip_bfloat16 h = __float2bfloat16(v);
  ushort s;
  __builtin_memcpy(&s, &h, 2);
  return s;
}

// ---------------------------------------------------------------------------
// K0: pack weights into MFMA B-fragment layouts; zero BN sums.
__global__ __launch_bounds__(256) void k_gen(const float* __restrict__ cw,
                                             const float* __restrict__ pw,
                                             const float* __restrict__ gw1,
                                             ushort* __restrict__ bfrag,
                                             ushort* __restrict__ pwf,
                                             ushort* __restrict__ bfragG,
                                             float* __restrict__ sums) {
  int idx = blockIdx.x * 256 + threadIdx.x;
  if (idx < 17) sums[idx] = 0.f;
  if (idx < 13312) {
    int j = idx & 7, lane = (idx >> 3) & 63, nt = (idx >> 9) & 1, s = idx >> 10;
    int quad = lane >> 4, col = lane & 15;
    int k = s * 32 + quad * 8 + j;
    int n = nt * 16 + col;
    float v = (k < 400) ? cw[(n * CC + (k & 15)) * 25 + (k >> 4)] : 0.f;
    bfrag[idx] = f2bfu(v);
  } else if (idx < 13824) {
    int i2 = idx - 13312;
    int j = i2 & 7, lane = i2 >> 3;
    int quad = lane >> 4, col = lane & 15;
    float v = (col < NH) ? pw[col * DCH + quad * 8 + j] : 0.f;
    pwf[i2] = f2bfu(v);
  } else if (idx < 16384) {
    int i3 = idx - 13824;
    int j = i3 & 7, lane = (i3 >> 3) & 63, s = i3 >> 9;  // s<5
    int quad = lane >> 4, col = lane & 15;
    int k = s * 32 + quad * 8 + j;
    float v = 0.f;
    if (k < 144 && col < GC) v = gw1[(col * CC + (k & 15)) * 9 + (k >> 4)];
    bfragG[i3] = f2bfu(v);
  }
}

// ---------------------------------------------------------------------------
// K1: gate network via MFMA (3x3 conv 16->8 + pool + FC + sigmoid).
// Writes ONLY gate2[b][c][t]. One block = (b,t). float4 staging loads.
__global__ __launch_bounds__(256, 4) void k_gate(
    const float* __restrict__ prev, const float* __restrict__ curr,
    const ushort* __restrict__ bfragG, const float* __restrict__ gb1,
    const float* __restrict__ gw2, const float* __restrict__ gb2,
    float* __restrict__ gate2) {
  __shared__ __align__(16) ushort img[8 * PSG];
  __shared__ float redg[64];
  __shared__ float pooled[16];

  int tid = threadIdx.x;
  int lane = tid & 63, w = tid >> 6;
  int bt = blockIdx.x;
  int b = bt >> 8, t = bt & 255;
  int quad = lane >> 4, col = lane & 15;
  int qh = quad >> 1, icb = (quad & 1) * 8;

  // zero image: 8*PSG ushorts = PSG uint4
  for (int i = tid; i < PSG; i += 256) ((uint4*)img)[i] = (uint4){0, 0, 0, 0};
  __syncthreads();

  // stage: pair-interleaved fill; float4 loads (4 px x 2 ch), b128 writes
#pragma unroll
  for (int it = 0; it < 4; ++it) {
    int E = it * 256 + tid;     // 0..1023
    int cp = E >> 7, g = E & 127;
    int l0 = g * 4;
    const float* src = (cp < 4) ? prev : curr;
    int chb = (cp & 3) * 2;
    const float* p0 = src + ((size_t)(b * NH + chb) * TT + t) * LL + l0;
    float4 f0 = *(const float4*)p0;
    float4 f1 = *(const float4*)(p0 + (size_t)TT * LL);
    unsigned w0 = (unsigned)f2bfu(f0.x) | ((unsigned)f2bfu(f1.x) << 16);
    unsigned w1 = (unsigned)f2bfu(f0.y) | ((unsigned)f2bfu(f1.y) << 16);
    unsigned w2 = (unsigned)f2bfu(f0.z) | ((unsigned)f2bfu(f1.z) << 16);
    unsigned w3 = (unsigned)f2bfu(f0.w) | ((unsigned)f2bfu(f1.w) << 16);
    int r = l0 >> 5, x = l0 & 31;
    int slot = (r + 1) * 48 + 8 + x;
    *(uint4*)&img[cp * PSG + slot * 2] = (uint4){w0, w1, w2, w3};
  }
  __syncthreads();

  // K-loop: 5 steps of K=32 (2 taps x 16 ic)
  f32x4 acc[8];
#pragma unroll
  for (int mi = 0; mi < 8; ++mi) acc[mi] = (f32x4){0.f, 0.f, 0.f, 0.f};
  int mtbase = w * 8;
  int ab[8];
#pragma unroll
  for (int mi = 0; mi < 8; ++mi) {
    int mt = mtbase + mi;
    int py = mt >> 1, px = ((mt & 1) << 4) + col;
    ab[mi] = (icb >> 1) * PSG + (py * 48 + 7 + px) * 2;
  }
  const int offE[5] = {0, 2, 49, 96, 98};
  const int offO[5] = {1, 48, 50, 97, 98};  // last = dummy (B zero)
  const s8b* bG = (const s8b*)bfragG;
#pragma unroll
  for (int s = 0; s < 5; ++s) {
    s8b bf = bG[s * 64 + lane];
    int off2 = (qh ? offO[s] : offE[s]) * 2;
#pragma unroll
    for (int mi = 0; mi < 8; ++mi) {
      union { unsigned u[4]; s8b v; } A;
      int a0 = ab[mi] + off2;
#pragma unroll
      for (int p = 0; p < 4; ++p) A.u[p] = *(const unsigned*)&img[a0 + p * PSG];
      acc[mi] = __builtin_amdgcn_mfma_f32_16x16x32_bf16(A.v, bf, acc[mi], 0, 0, 0);
    }
  }

  // pool: mean over 512 pixels of relu(conv + b1), per oc (=col)
  float gb1c = (col < GC) ? gb1[col] : 0.f;
  float s = 0.f;
#pragma unroll
  for (int mi = 0; mi < 8; ++mi)
#pragma unroll
    for (int r = 0; r < 4; ++r) s += fmaxf(acc[mi][r] + gb1c, 0.f);
  s += __shfl_down(s, 16, 64);
  s += __shfl_down(s, 32, 64);
  if (lane < 16) redg[w * 16 + lane] = s;
  __syncthreads();
  if (tid < 16)
    pooled[tid] = (redg[tid] + redg[16 + tid] + redg[32 + tid] + redg[48 + tid]) *
                  (1.0f / (float)LL);
  __syncthreads();
  if (tid < 16) {
    float z = gb2[tid];
#pragma unroll
    for (int i = 0; i < GC; ++i) z = fmaf(pooled[i], gw2[tid * GC + i], z);
    gate2[(b * CC + tid) * TT + t] = 1.f / (1.f + __expf(-z));
  }
}

// ---------------------------------------------------------------------------
// K2: single-pass exclusive cumsum over t of attn*gate, bf16 out. [r9 verbatim]
__global__ __launch_bounds__(256) void k_cum(const float* __restrict__ prev,
                                             const float* __restrict__ curr,
                                             const float* __restrict__ gate2,
                                             ushort* __restrict__ cum) {
  int idx = blockIdx.x * 256 + threadIdx.x;
  int l = idx & 511;
  int c = (idx >> 9) & 15;
  int b = idx >> 13;
  const float* src = (c < NH) ? prev : curr;
  const float* a = src + (size_t)(b * NH + (c & 7)) * TT * LL + l;
  const float* g = gate2 + (b * CC + c) * TT;
  ushort* o = cum + (size_t)(b * CC + c) * TT * LL + l;
  float run = 0.f;
#pragma unroll 16
  for (int t = 0; t < TT; ++t) {
    float av = a[(size_t)t * LL];
    float gv = g[t];
    o[(size_t)t * LL] = f2bfu(run);  // exclusive
    run = fmaf(av, gv, run);
  }
}

// ---------------------------------------------------------------------------
// K3: MFMA implicit-GEMM 5x5 conv 16->32 (+bias+relu), mask, 1x1 proj MFMA,
// BN-sum accumulation. One block = one (b,t) image.
// LDS image = quad-interleave (r6 K-loop, PASS-verified); staging reads the
// r7 cum[b][c][t][l] layout and packs in-register (keeps clean HBM traffic).
__global__ __launch_bounds__(256, 4) void k_cov(
    const ushort* __restrict__ cum, const ushort* __restrict__ bfrag,
    const ushort* __restrict__ pwf, const float* __restrict__ cb,
    const int* __restrict__ mask, float* __restrict__ out,
    float* __restrict__ sums) {
  __shared__ __align__(16) ushort img[4 * PSC4 * 4];  // 4 planes * 964 * 8B
  __shared__ __align__(16) ushort scr[4 * 640];       // per wave 32 oc * 20
  __shared__ float redp[128];
  __shared__ float redc[4];

  int tid = threadIdx.x;
  int lane = tid & 63, w = tid >> 6;
  int bt = blockIdx.x;
  int b = bt >> 8, t = bt & 255;
  int quad = lane >> 4, col = lane & 15;
  int qh = quad >> 1;
  int p0pl = (quad & 1) * 2;

  // zero image: 4*964*8 B = 1928 uint4
  for (int i = tid; i < 1928; i += 256) ((uint4*)img)[i] = (uint4){0, 0, 0, 0};
  __syncthreads();

  // stage: per iteration read 4 channel-rows (2 px each), pack to 2 quad
  // entries, one b128 write. 4 global dword loads + 6 VALU + 1 ds_write_b128.
#pragma unroll
  for (int it = 0; it < 4; ++it) {
    int E = it * 256 + tid;      // 0..1023
    int q = E >> 8;              // plane = channel quad
    int e = E & 255;
    int l0 = e * 2;
    const ushort* p0 = cum + ((size_t)(b * CC + q * 4) * TT + t) * LL + l0;
    unsigned v0 = *(const unsigned*)p0;
    unsigned v1 = *(const unsigned*)(p0 + (size_t)TT * LL);
    unsigned v2 = *(const unsigned*)(p0 + (size_t)2 * TT * LL);
    unsigned v3 = *(const unsigned*)(p0 + (size_t)3 * TT * LL);
    unsigned w0 = (v0 & 0xFFFFu) | (v1 << 16);
    unsigned w1 = (v2 & 0xFFFFu) | (v3 << 16);
    unsigned w2 = (v0 >> 16) | (v1 & 0xFFFF0000u);
    unsigned w3 = (v2 >> 16) | (v3 & 0xFFFF0000u);
    int r = l0 >> 5, x = l0 & 31;
    int slot = (r + 2) * 48 + 8 + x;
    *(uint4*)&img[(q * PSC4 + slot) * 4] = (uint4){w0, w1, w2, w3};
  }
  __syncthreads();

  // K-loop: 13 steps of K=32; A-fragment = 2 x ds_read_b64  [r6-verified]
  f32x4 acc[8][2];
#pragma unroll
  for (int mi = 0; mi < 8; ++mi) {
    acc[mi][0] = (f32x4){0.f, 0.f, 0.f, 0.f};
    acc[mi][1] = (f32x4){0.f, 0.f, 0.f, 0.f};
  }
  int mtbase = w * 8;
  int ab[8];
#pragma unroll
  for (int mi = 0; mi < 8; ++mi) {
    int mt = mtbase + mi;
    int py = mt >> 1, px = ((mt & 1) << 4) + col;
    ab[mi] = p0pl * PSC4 + py * 48 + 6 + px;   // entry units
  }
  const int offE[13] = {0, 2, 4, 49, 51, 96, 98, 100, 145, 147, 192, 194, 196};
  const int offO[13] = {1, 3, 48, 50, 52, 97, 99, 144, 146, 148, 193, 195, 196};
  const s8b* bfr = (const s8b*)bfrag;
#pragma unroll
  for (int s = 0; s < 13; ++s) {
    s8b bf0 = bfr[(s * 2) * 64 + lane];
    s8b bf1 = bfr[(s * 2 + 1) * 64 + lane];
    int off = qh ? offO[s] : offE[s];
#pragma unroll
    for (int mi = 0; mi < 8; ++mi) {
      union { uint2 u2[2]; s8b v; } A;
      int e0 = ab[mi] + off;
      A.u2[0] = *(const uint2*)&img[e0 * 4];
      A.u2[1] = *(const uint2*)&img[(e0 + PSC4) * 4];
      acc[mi][0] = __builtin_amdgcn_mfma_f32_16x16x32_bf16(A.v, bf0, acc[mi][0], 0, 0, 0);
      acc[mi][1] = __builtin_amdgcn_mfma_f32_16x16x32_bf16(A.v, bf1, acc[mi][1], 0, 0, 0);
    }
  }

  // epilogue: wave-private scr round-trip (C-layout -> A-layout), proj MFMA,
  // mask, store, BN partials.  [r8/r9 verbatim]
  int wb = w * 640;
  float cb0 = cb[col], cb1 = cb[col + 16];
  s8b pf = ((const s8b*)pwf)[lane];
  float psum = 0.f, psq = 0.f, pcnt = 0.f;
  float* outbase = out + ((size_t)(b * NH + col) * TT + t) * LL;  // col<8 only
  const int* mrow = mask + b * LL;
#pragma unroll
  for (int mi = 0; mi < 8; ++mi) {
    int mt = mtbase + mi;
    ushort w0[4], w1[4];
#pragma unroll
    for (int r = 0; r < 4; ++r) {
      w0[r] = f2bfu(fmaxf(acc[mi][0][r] + cb0, 0.f));
      w1[r] = f2bfu(fmaxf(acc[mi][1][r] + cb1, 0.f));
    }
    uint2 pk0, pk1;
    __builtin_memcpy(&pk0, w0, 8);
    __builtin_memcpy(&pk1, w1, 8);
    *(uint2*)&scr[wb + col * 20 + quad * 4] = pk0;          // oc=col
    *(uint2*)&scr[wb + (col + 16) * 20 + quad * 4] = pk1;   // oc=col+16
    ushort u[8];
#pragma unroll
    for (int e = 0; e < 8; ++e) u[e] = scr[wb + (quad * 8 + e) * 20 + col];
    s8b a2;
    __builtin_memcpy(&a2, u, 16);
    f32x4 zero = {0.f, 0.f, 0.f, 0.f};
    f32x4 d2 = __builtin_amdgcn_mfma_f32_16x16x32_bf16(a2, pf, zero, 0, 0, 0);
    int4 m4 = *(const int4*)(mrow + mt * 16 + quad * 4);
    float k0 = m4.x ? 0.f : 1.f;
    float k1 = m4.y ? 0.f : 1.f;
    float k2 = m4.z ? 0.f : 1.f;
    float k3 = m4.w ? 0.f : 1.f;
    if (col < NH) {
      float* op = outbase + mt * 16 + quad * 4;
      float v0 = d2[0] * k0; op[0] = v0; psum += v0; psq += v0 * v0;
      float v1 = d2[1] * k1; op[1] = v1; psum += v1; psq += v1 * v1;
      float v2 = d2[2] * k2; op[2] = v2; psum += v2; psq += v2 * v2;
      float v3 = d2[3] * k3; op[3] = v3; psum += v3; psq += v3 * v3;
    }
    if (col == 0) pcnt += k0 + k1 + k2 + k3;
  }

  psum += __shfl_down(psum, 16, 64); psum += __shfl_down(psum, 32, 64);
  psq  += __shfl_down(psq, 16, 64);  psq  += __shfl_down(psq, 32, 64);
  pcnt += __shfl_down(pcnt, 16, 64); pcnt += __shfl_down(pcnt, 32, 64);
  if (lane < 16) {
    redp[(w * 16 + lane) * 2] = psum;
    redp[(w * 16 + lane) * 2 + 1] = psq;
    if (lane == 0) redc[w] = pcnt;
  }
  __syncthreads();
  if (tid < 17) {
    float v;
    if (tid < 8) {
      v = redp[tid * 2] + redp[(16 + tid) * 2] + redp[(32 + tid) * 2] + redp[(48 + tid) * 2];
    } else if (tid < 16) {
      int nh = tid - 8;
      v = redp[nh * 2 + 1] + redp[(16 + nh) * 2 + 1] + redp[(32 + nh) * 2 + 1] + redp[(48 + nh) * 2 + 1];
    } else {
      v = redc[0] + redc[1] + redc[2] + redc[3];
    }
    atomicAdd(&sums[tid], v);
  }
}

// ---------------------------------------------------------------------------
// K4: masked BN normalize in-place. 8 floats/thread. [r9 verbatim]
__global__ __launch_bounds__(256) void k_bn(
    float* __restrict__ out, const float* __restrict__ sums,
    const int* __restrict__ mask, const float* __restrict__ gamma,
    const float* __restrict__ beta) {
  __shared__ float sc[NH], sh[NH];
  int tid = threadIdx.x;
  if (tid < NH) {
    float cnt = sums[16];
    float mean = sums[tid] / cnt;
    float var = sums[NH + tid] / cnt - mean * mean;
    float inv = rsqrtf(var + 1e-5f) * gamma[tid];
    sc[tid] = inv;
    sh[tid] = fmaf(-mean, inv, beta[tid]);
  }
  __syncthreads();
  size_t e = ((size_t)blockIdx.x * 256 + tid) * 8;  // 8 consecutive l
  int l = (int)(e & (LL - 1));
  int bn = (int)(e >> 17);
  int n = bn & 7;
  int b = bn >> 3;
  const int4 mv0 = *(const int4*)(mask + b * LL + l);
  const int4 mv1 = *(const int4*)(mask + b * LL + l + 4);
  float4 v0 = *(float4*)(out + e);
  float4 v1 = *(float4*)(out + e + 4);
  float s = sc[n], h = sh[n];
  v0.x = mv0.x ? v0.x : fmaf(v0.x, s, h);
  v0.y = mv0.y ? v0.y : fmaf(v0.y, s, h);
  v0.z = mv0.z ? v0.z : fmaf(v0.z, s, h);
  v0.w = mv0.w ? v0.w : fmaf(v0.w, s, h);
  v1.x = mv1.x ? v1.x : fmaf(v1.x, s, h);
  v1.y = mv1.y ? v1.y : fmaf(v1.y, s, h);
  v1.z = mv1.z ? v1.z : fmaf(v1.z, s, h);
  v1.w = mv1.w ? v1.w : fmaf(v1.w, s, h);
  *(float4*)(out + e) = v0;
  *(float4*)(out + e + 4) = v1;
}

// ---------------------------------------------------------------------------
extern "C" void kernel_launch(void* const* d_in, const int* in_sizes, int n_in,
                              void* d_out, int out_size, void* d_ws, size_t ws_size,
                              hipStream_t stream) {
  const float* prev   = (const float*)d_in[0];
  const int*   mask   = (const int*)d_in[1];
  const float* curr   = (const float*)d_in[3];
  const float* conv_w = (const float*)d_in[5];
  const float* conv_b = (const float*)d_in[6];
  const float* proj_w = (const float*)d_in[7];
  const float* g_w1   = (const float*)d_in[8];
  const float* g_b1   = (const float*)d_in[9];
  const float* g_w2   = (const float*)d_in[10];
  const float* g_b2   = (const float*)d_in[11];
  const float* bn_g   = (const float*)d_in[12];
  const float* bn_b   = (const float*)d_in[13];
  float* out = (float*)d_out;

  char* ws = (char*)d_ws;
  ushort* bfrag  = (ushort*)(ws);                    // 26624 B
  ushort* pwf    = (ushort*)(ws + 26624);            // 1024 B
  ushort* bfragG = (ushort*)(ws + 27648);            // 5120 B
  float*  sums   = (float*)(ws + 32768);             // 68 B
  float*  gate2  = (float*)(ws + 36864);             // 131072 B  [b][c][t]
  ushort* cum    = (ushort*)(ws + 36864 + 131072);   // 33554432 B [b][c][t][l]

  k_gen<<<64, 256, 0, stream>>>(conv_w, proj_w, g_w1, bfrag, pwf, bfragG, sums);
  k_gate<<<BB * TT, 256, 0, stream>>>(prev, curr, bfragG, g_b1, g_w2, g_b2, gate2);
  k_cum<<<(BB * CC * LL) / 256, 256, 0, stream>>>(prev, curr, gate2, cum);
  k_cov<<<BB * TT, 256, 0, stream>>>(cum, bfrag, pwf, conv_b, mask, out, sums);
  k_bn<<<(BB * NH * TT * LL) / (256 * 8), 256, 0, stream>>>(out, sums, mask, bn_g, bn_b);
}